// Round 6
// baseline (214.753 us; speedup 1.0000x reference)
//
#include <hip/hip_runtime.h>
#include <hip/hip_cooperative_groups.h>
#include <math.h>

namespace cg = cooperative_groups;

#define HID 512
#define IN_FEAT 342
#define OUTD 311
#define BATCH 256
#define KP0 352           // layer-0 padded K (11 chunks of 32)
#define MP2 320           // layer-2 padded M
#define XROW (IN_FEAT + 1)
#define LSTRIDE 264       // LDS row stride in u16 (33 x 16B, odd -> conflict-free)

typedef unsigned short u16;
typedef short bf16x8 __attribute__((ext_vector_type(8)));
typedef float f32x4 __attribute__((ext_vector_type(4)));

__device__ __forceinline__ u16 f2bf_rne(float v) {
    unsigned int x = __float_as_uint(v);
    unsigned int r = (x + 0x7fffu + ((x >> 16) & 1u)) >> 16;
    return (u16)r;
}
__device__ __forceinline__ float bf2f(u16 u) {
    return __uint_as_float(((unsigned int)u) << 16);
}

// prep item space (8-wide chunks)
#define C0 (4 * 512 * 44)
#define C1 (4 * 512 * 64)
#define C2 (4 * 320 * 64)
#define CX (256 * 44)
#define PREP_TOT (C0 + C1 + C2 + CX + 256)

union U8 { u16 u[8]; uint4 v; };

union SharedU {
    u16 h[2][32 * LSTRIDE];     // staged H tile: [hi/lo][row*LSTRIDE + col], 33 KB
    float acc[4][32][17];       // cross-slice blend buffer (reused after barrier)
};

struct Params {
    const float *x, *W0, *b0, *W1, *b1, *W2, *b2;
    float* out;
    u16 *whi0, *wlo0, *whi1, *wlo1, *whi2, *wlo2;
    u16 *h0hi, *h0lo, *hahi, *halo, *hbhi, *hblo;
    float* dcoef;
};

// ---------------- layer phase: 256 thr, wave=slice, 2 b-tiles/wave ----------------
__device__ __forceinline__ void layer_phase(
    SharedU& sm,
    const u16* __restrict__ Whi, const u16* __restrict__ Wlo, int wstride, int Mp,
    const u16* __restrict__ Hhi, const u16* __restrict__ Hlo, int hstride, int nch,
    const float* __restrict__ bias, const float* __restrict__ dcoef, int Mb,
    int OT, int FINAL,
    u16* __restrict__ Ohi, u16* __restrict__ Olo, float* __restrict__ outp)
{
    const int unit = (int)blockIdx.x;
    if (unit >= OT * 8) return;
    int ot, bq;
    if (OT == 32) { ot = unit & 31; bq = unit >> 5; }
    else          { ot = unit % OT; bq = unit / OT; }
    const int o0 = ot * 16;
    const int b0 = bq * 32;
    const int tid = (int)threadIdx.x;
    const int lane = tid & 63;
    const int s = tid >> 6;          // wave -> slice
    const int m = lane & 15;
    const int q = lane >> 4;

    f32x4 a0[2], a1[2], a2[2];
#pragma unroll
    for (int bt = 0; bt < 2; ++bt) {
        a0[bt] = (f32x4){0.f, 0.f, 0.f, 0.f};
        a1[bt] = (f32x4){0.f, 0.f, 0.f, 0.f};
        a2[bt] = (f32x4){0.f, 0.f, 0.f, 0.f};
    }

    const u16* wph = Whi + ((size_t)s * Mp + o0 + m) * wstride + q * 8;
    const u16* wpl = Wlo + ((size_t)s * Mp + o0 + m) * wstride + q * 8;

    for (int c0 = 0; c0 < nch; c0 += 8) {
        const int rc = (nch - c0 < 8) ? (nch - c0) : 8;
        __syncthreads();
        // stage H rows b0..b0+31, chunks c0..c0+rc-1 (hi & lo)
        const int tot = 32 * rc * 4;               // uint4 items per buffer
        for (int idx = tid; idx < tot; idx += 256) {
            int r = idx / (rc * 4);
            int c = idx - r * (rc * 4);
            size_t g = (size_t)(b0 + r) * hstride + c0 * 32 + c * 8;
            *reinterpret_cast<uint4*>(&sm.h[0][r * LSTRIDE + c * 8]) =
                *reinterpret_cast<const uint4*>(Hhi + g);
            *reinterpret_cast<uint4*>(&sm.h[1][r * LSTRIDE + c * 8]) =
                *reinterpret_cast<const uint4*>(Hlo + g);
        }
        __syncthreads();
        for (int cc = 0; cc < rc; ++cc) {
            bf16x8 ah = *reinterpret_cast<const bf16x8*>(wph + (size_t)(c0 + cc) * 32);
            bf16x8 al = *reinterpret_cast<const bf16x8*>(wpl + (size_t)(c0 + cc) * 32);
#pragma unroll
            for (int bt = 0; bt < 2; ++bt) {
                const u16* base = &sm.h[0][(bt * 16 + m) * LSTRIDE + cc * 32 + q * 8];
                bf16x8 bh = *reinterpret_cast<const bf16x8*>(base);
                bf16x8 bl = *reinterpret_cast<const bf16x8*>(base + 32 * LSTRIDE);
                a0[bt] = __builtin_amdgcn_mfma_f32_16x16x32_bf16(ah, bh, a0[bt], 0, 0, 0);
                a1[bt] = __builtin_amdgcn_mfma_f32_16x16x32_bf16(ah, bl, a1[bt], 0, 0, 0);
                a2[bt] = __builtin_amdgcn_mfma_f32_16x16x32_bf16(al, bh, a2[bt], 0, 0, 0);
            }
        }
    }
    __syncthreads();   // all LDS H reads done; reuse union as blend buffer

    // wave-phase blend: d_s(b) * (sum + bias_s)
    float bb[4];
#pragma unroll
    for (int r = 0; r < 4; ++r) {
        int o = o0 + q * 4 + r;
        bb[r] = (o < Mb) ? bias[(size_t)s * Mb + o] : 0.f;
    }
    const float ds0 = dcoef[(size_t)(b0 + m) * 4 + s];
    const float ds1 = dcoef[(size_t)(b0 + 16 + m) * 4 + s];
#pragma unroll
    for (int bt = 0; bt < 2; ++bt) {
        f32x4 sum = a0[bt] + a1[bt] + a2[bt];
        const float dsv = bt ? ds1 : ds0;
#pragma unroll
        for (int r = 0; r < 4; ++r)
            sm.acc[s][bt * 16 + m][q * 4 + r] = dsv * (sum[r] + bb[r]);
    }
    __syncthreads();

    // reduce slices, activate, store: 32 b x 16 o outputs
    for (int idx = tid; idx < 512; idx += 256) {
        int b_l = idx >> 4, o_l = idx & 15;
        float v = sm.acc[0][b_l][o_l] + sm.acc[1][b_l][o_l]
                + sm.acc[2][b_l][o_l] + sm.acc[3][b_l][o_l];
        int o = o0 + o_l, b = b0 + b_l;
        if (!FINAL) {
            float e = (v > 0.f) ? v : expm1f(v);
            u16 h = f2bf_rne(e);
            Ohi[(size_t)b * HID + o] = h;
            Olo[(size_t)b * HID + o] = f2bf_rne(e - bf2f(h));
        } else if (o < OUTD) {
            outp[(size_t)b * OUTD + o] = v;
        }
    }
}

// ---------------- the single cooperative kernel ----------------
__global__ __launch_bounds__(256) void pfn_coop(Params p)
{
    __shared__ SharedU sm;
    cg::grid_group grid = cg::this_grid();

    // ---- phase 0: prep (grid-stride over item space) ----
    for (int i = (int)blockIdx.x * 256 + (int)threadIdx.x; i < PREP_TOT; i += 256 * 256) {
        if (i >= C0 + C1 + C2 + CX) {            // dcoef
            int b = i - (C0 + C1 + C2 + CX);
            float ps = 4.f * p.x[(size_t)b * XROW + IN_FEAT];
            float fl = floorf(ps);
            float mu = ps - fl;
            int i1 = ((int)fl) & 3;
            float mu2 = mu * mu, mu3 = mu2 * mu;
            float c0 = -0.5f * mu3 + mu2 - 0.5f * mu;
            float c1 = 1.5f * mu3 - 2.5f * mu2 + 1.0f;
            float c2 = -1.5f * mu3 + 2.0f * mu2 + 0.5f * mu;
            float c3 = 0.5f * mu3 - 0.5f * mu2;
            float d[4];
            d[(i1 + 3) & 3] = c0;
            d[i1]           = c1;
            d[(i1 + 1) & 3] = c2;
            d[(i1 + 2) & 3] = c3;
            *reinterpret_cast<float4*>(p.dcoef + b * 4) = make_float4(d[0], d[1], d[2], d[3]);
            continue;
        }
        float src[8];
        u16 *dhi, *dlo; size_t doff;
        if (i < C0) {                            // W0 -> [4*512][352]
            int row = i / 44, c = i - row * 44;
            int k = c * 8;
#pragma unroll
            for (int j = 0; j < 8; j++) {
                int kk = k + j;
                src[j] = (kk < IN_FEAT) ? p.W0[(size_t)row * IN_FEAT + kk] : 0.f;
            }
            dhi = p.whi0; dlo = p.wlo0; doff = (size_t)row * KP0 + k;
        } else if (i < C0 + C1) {                // W1 -> [4*512][512]
            int l = i - C0;
            int row = l >> 6, c = l & 63;
            int k = c * 8;
            const float* sp = p.W1 + (size_t)row * HID + k;
#pragma unroll
            for (int j = 0; j < 8; j++) src[j] = sp[j];
            dhi = p.whi1; dlo = p.wlo1; doff = (size_t)row * HID + k;
        } else if (i < C0 + C1 + C2) {           // W2 -> [4*320][512] (rows >=311 zero)
            int l = i - C0 - C1;
            int row = l >> 6, c = l & 63;
            int k = c * 8;
            int s = row / 320, o = row - s * 320;
            if (o < OUTD) {
                const float* sp = p.W2 + ((size_t)s * OUTD + o) * HID + k;
#pragma unroll
                for (int j = 0; j < 8; j++) src[j] = sp[j];
            } else {
#pragma unroll
                for (int j = 0; j < 8; j++) src[j] = 0.f;
            }
            dhi = p.whi2; dlo = p.wlo2; doff = (size_t)row * HID + k;
        } else {                                 // x -> H0 [256][352]
            int l = i - C0 - C1 - C2;
            int b = l / 44, c = l - b * 44;
            int k = c * 8;
#pragma unroll
            for (int j = 0; j < 8; j++) {
                int kk = k + j;
                src[j] = (kk < IN_FEAT) ? p.x[(size_t)b * XROW + kk] : 0.f;
            }
            dhi = p.h0hi; dlo = p.h0lo; doff = (size_t)b * KP0 + k;
        }
        U8 hi, lo;
#pragma unroll
        for (int j = 0; j < 8; j++) {
            u16 h = f2bf_rne(src[j]);
            hi.u[j] = h;
            lo.u[j] = f2bf_rne(src[j] - bf2f(h));
        }
        *reinterpret_cast<uint4*>(dhi + doff) = hi.v;
        *reinterpret_cast<uint4*>(dlo + doff) = lo.v;
    }

    grid.sync();
    // ---- layer 0: K=352 (11 chunks), M=512 ----
    layer_phase(sm, p.whi0, p.wlo0, KP0, HID, p.h0hi, p.h0lo, KP0, 11,
                p.b0, p.dcoef, HID, 32, 0, p.hahi, p.halo, nullptr);
    grid.sync();
    // ---- layer 1: K=512 (16 chunks), M=512 ----
    layer_phase(sm, p.whi1, p.wlo1, HID, HID, p.hahi, p.halo, HID, 16,
                p.b1, p.dcoef, HID, 32, 0, p.hbhi, p.hblo, nullptr);
    grid.sync();
    // ---- layer 2: K=512, M=311 (Mp=320, 20 o-tiles) ----
    layer_phase(sm, p.whi2, p.wlo2, HID, MP2, p.hbhi, p.hblo, HID, 16,
                p.b2, p.dcoef, OUTD, 20, 1, nullptr, nullptr, p.out);
}

extern "C" void kernel_launch(void* const* d_in, const int* in_sizes, int n_in,
                              void* d_out, int out_size, void* d_ws, size_t ws_size,
                              hipStream_t stream) {
    char* pw = (char*)d_ws;
    auto alloc = [&](size_t bytes) { char* r = pw; pw += (bytes + 255) & ~(size_t)255; return r; };

    Params p;
    p.x  = (const float*)d_in[0];
    p.W0 = (const float*)d_in[1];
    p.b0 = (const float*)d_in[2];
    p.W1 = (const float*)d_in[3];
    p.b1 = (const float*)d_in[4];
    p.W2 = (const float*)d_in[5];
    p.b2 = (const float*)d_in[6];
    p.out = (float*)d_out;

    p.dcoef = (float*)alloc(BATCH * 4 * sizeof(float));
    p.whi0 = (u16*)alloc((size_t)4 * HID * KP0 * 2);
    p.wlo0 = (u16*)alloc((size_t)4 * HID * KP0 * 2);
    p.whi1 = (u16*)alloc((size_t)4 * HID * HID * 2);
    p.wlo1 = (u16*)alloc((size_t)4 * HID * HID * 2);
    p.whi2 = (u16*)alloc((size_t)4 * MP2 * HID * 2);
    p.wlo2 = (u16*)alloc((size_t)4 * MP2 * HID * 2);
    p.h0hi = (u16*)alloc((size_t)BATCH * KP0 * 2);
    p.h0lo = (u16*)alloc((size_t)BATCH * KP0 * 2);
    p.hahi = (u16*)alloc((size_t)BATCH * HID * 2);
    p.halo = (u16*)alloc((size_t)BATCH * HID * 2);
    p.hbhi = (u16*)alloc((size_t)BATCH * HID * 2);
    p.hblo = (u16*)alloc((size_t)BATCH * HID * 2);

    void* args[] = { &p };
    hipLaunchCooperativeKernel(reinterpret_cast<const void*>(&pfn_coop),
                               dim3(256), dim3(256), args, 0, stream);
}

// Round 7
// 105.546 us; speedup vs baseline: 2.0347x; 2.0347x over previous
//
#include <hip/hip_runtime.h>
#include <math.h>

#define HID 512
#define IN_FEAT 342
#define OUTD 311
#define BATCH 256
#define XROW (IN_FEAT + 1)
#define KP0 352            // layer-0 padded K (11 chunks of 32)

typedef unsigned short u16;
typedef short bf16x8 __attribute__((ext_vector_type(8)));
typedef float f32x4 __attribute__((ext_vector_type(4)));

__device__ __forceinline__ u16 f2bf_rne(float v) {
    unsigned int x = __float_as_uint(v);
    unsigned int r = (x + 0x7fffu + ((x >> 16) & 1u)) >> 16;
    return (u16)r;
}
__device__ __forceinline__ float bf2f(u16 u) {
    return __uint_as_float(((unsigned int)u) << 16);
}

// in-register fp32 -> (hi RNE, lo trunc) split of 8 elems
__device__ __forceinline__ void cvt8(const float* v, bf16x8& hi, bf16x8& lo) {
#pragma unroll
    for (int j = 0; j < 8; j++) {
        unsigned int xu = __float_as_uint(v[j]);
        unsigned int rnd = xu + 0x7fffu + ((xu >> 16) & 1u);
        hi[j] = (short)(rnd >> 16);
        float lof = v[j] - __uint_as_float(rnd & 0xffff0000u);
        lo[j] = (short)(__float_as_uint(lof) >> 16);   // trunc: |err| <= 2^-17 rel
    }
}

// ============ fused layer, fp32 weights streamed + converted in-register ============
// out[b][o] = act( sum_s d_s(b) * ( sum_k W[s][o][k]*H[b][k] + bias[s][o] ) )
// grid (BATCH/16, Mp/16); block 256 = 4 waves; wave s computes slice s; LDS blend.
// KCH: number of 32-wide k-chunks. KLDS: LDS row stride in u16 (odd 16B quads).
// L0: H comes from x fp32 (converted in prologue); else from Hhi/Hlo (stride HID).
template<int KCH, int KLDS, int FINAL, int L0>
__global__ __launch_bounds__(256, 2) void layer_direct(
    const float* __restrict__ W,      // fp32 [4][Mreal][Kw]
    int Kw, int Mreal, int Mb,
    const float* __restrict__ x,      // [256][343] (H-source for L0; phase col always)
    const u16* __restrict__ Hhi, const u16* __restrict__ Hlo,
    const float* __restrict__ bias,   // [4][Mb]
    u16* __restrict__ Ohi, u16* __restrict__ Olo, float* __restrict__ outp)
{
    union SharedU {
        u16 h[2][16 * KLDS];
        float acc[4][16][17];
    };
    __shared__ SharedU sm;

    const int tid = (int)threadIdx.x;
    const int b0 = (int)blockIdx.x * 16;
    const int o0 = (int)blockIdx.y * 16;

    // ---- stage H tile (16 rows x KCH*32, hi+lo) ----
    if (L0) {
        for (int idx = tid; idx < 16 * KP0; idx += 256) {
            int r = idx / KP0, k = idx - r * KP0;
            float v = (k < IN_FEAT) ? x[(size_t)(b0 + r) * XROW + k] : 0.f;
            u16 h = f2bf_rne(v);
            sm.h[0][r * KLDS + k] = h;
            sm.h[1][r * KLDS + k] = f2bf_rne(v - bf2f(h));
        }
    } else {
        constexpr int CH = KCH * 4;          // uint4 per row
        for (int idx = tid; idx < 16 * CH; idx += 256) {
            int r = idx / CH, c = idx - r * CH;
            size_t g = (size_t)(b0 + r) * HID + c * 8;
            *reinterpret_cast<uint4*>(&sm.h[0][r * KLDS + c * 8]) =
                *reinterpret_cast<const uint4*>(Hhi + g);
            *reinterpret_cast<uint4*>(&sm.h[1][r * KLDS + c * 8]) =
                *reinterpret_cast<const uint4*>(Hlo + g);
        }
    }
    __syncthreads();

    const int lane = tid & 63;
    const int s = tid >> 6;               // wave -> slice
    const int m = lane & 15;
    const int q = lane >> 4;

    // W row for this lane (clamp for padded M; garbage rows never stored)
    int orow = o0 + m;
    if (orow >= Mreal) orow = Mreal - 1;
    const float* wr = W + ((size_t)s * Mreal + orow) * Kw;

    const u16* hp = &sm.h[0][m * KLDS + q * 8];

    f32x4 a0 = {0.f, 0.f, 0.f, 0.f};
    f32x4 a1 = {0.f, 0.f, 0.f, 0.f};
    f32x4 a2 = {0.f, 0.f, 0.f, 0.f};

#pragma unroll
    for (int cc = 0; cc < KCH; ++cc) {
        const int kb = cc * 32 + q * 8;
        float v[8];
        if (L0) {
            if (cc < KCH - 1) {           // full chunk: float2 x4 (rows 8B-aligned)
#pragma unroll
                for (int t = 0; t < 4; t++) {
                    float2 f2 = *reinterpret_cast<const float2*>(wr + kb + t * 2);
                    v[t * 2] = f2.x; v[t * 2 + 1] = f2.y;
                }
            } else {                      // tail chunk: per-elem guard (Kw=342)
#pragma unroll
                for (int j = 0; j < 8; j++) {
                    int k = kb + j;
                    v[j] = (k < IN_FEAT) ? wr[k] : 0.f;
                }
            }
        } else {                          // rows 2048B-aligned: float4 x2
            float4 f4a = *reinterpret_cast<const float4*>(wr + kb);
            float4 f4b = *reinterpret_cast<const float4*>(wr + kb + 4);
            v[0] = f4a.x; v[1] = f4a.y; v[2] = f4a.z; v[3] = f4a.w;
            v[4] = f4b.x; v[5] = f4b.y; v[6] = f4b.z; v[7] = f4b.w;
        }
        bf16x8 ah, al;
        cvt8(v, ah, al);
        bf16x8 bh = *reinterpret_cast<const bf16x8*>(hp + cc * 32);
        bf16x8 bl = *reinterpret_cast<const bf16x8*>(hp + cc * 32 + 16 * KLDS);
        a0 = __builtin_amdgcn_mfma_f32_16x16x32_bf16(ah, bh, a0, 0, 0, 0);
        a1 = __builtin_amdgcn_mfma_f32_16x16x32_bf16(ah, bl, a1, 0, 0, 0);
        a2 = __builtin_amdgcn_mfma_f32_16x16x32_bf16(al, bh, a2, 0, 0, 0);
    }
    __syncthreads();   // LDS H reads done; reuse union as blend buffer

    // per-lane phase coeff d_s(b), b = b0+m  (s is wave-uniform)
    float ds;
    {
        float ps = 4.f * x[(size_t)(b0 + m) * XROW + IN_FEAT];
        float fl = floorf(ps);
        float mu = ps - fl;
        int i1 = ((int)fl) & 3;
        float mu2 = mu * mu, mu3 = mu2 * mu;
        float c0 = -0.5f * mu3 + mu2 - 0.5f * mu;
        float c1 = 1.5f * mu3 - 2.5f * mu2 + 1.0f;
        float c2 = -1.5f * mu3 + 2.0f * mu2 + 0.5f * mu;
        float c3 = 0.5f * mu3 - 0.5f * mu2;
        int k = (s + 1 - i1) & 3;         // slice s gets c[k]
        ds = (k == 0) ? c0 : (k == 1) ? c1 : (k == 2) ? c2 : c3;
    }

    f32x4 sum = a0 + a1 + a2;
#pragma unroll
    for (int r = 0; r < 4; ++r) {
        int o = o0 + q * 4 + r;
        float bb = (o < Mb) ? bias[(size_t)s * Mb + o] : 0.f;
        sm.acc[s][q * 4 + r][m] = ds * (sum[r] + bb);
    }
    __syncthreads();

    // reduce 4 slices, activate, store: thread -> (b_l = tid>>4, o_l = tid&15)
    const int o_l = tid & 15;
    const int b_l = tid >> 4;
    float vv = sm.acc[0][o_l][b_l] + sm.acc[1][o_l][b_l]
             + sm.acc[2][o_l][b_l] + sm.acc[3][o_l][b_l];
    const int o = o0 + o_l;
    const int b = b0 + b_l;
    if (!FINAL) {
        float e = (vv > 0.f) ? vv : expm1f(vv);
        u16 h = f2bf_rne(e);
        Ohi[(size_t)b * HID + o] = h;
        Olo[(size_t)b * HID + o] = f2bf_rne(e - bf2f(h));
    } else if (o < OUTD) {
        outp[(size_t)b * OUTD + o] = vv;
    }
}

extern "C" void kernel_launch(void* const* d_in, const int* in_sizes, int n_in,
                              void* d_out, int out_size, void* d_ws, size_t ws_size,
                              hipStream_t stream) {
    const float* x  = (const float*)d_in[0];
    const float* W0 = (const float*)d_in[1];
    const float* b0 = (const float*)d_in[2];
    const float* W1 = (const float*)d_in[3];
    const float* b1 = (const float*)d_in[4];
    const float* W2 = (const float*)d_in[5];
    const float* b2 = (const float*)d_in[6];
    float* out = (float*)d_out;

    char* pw = (char*)d_ws;
    auto alloc = [&](size_t bytes) { char* r = pw; pw += (bytes + 255) & ~(size_t)255; return r; };
    u16* hahi = (u16*)alloc((size_t)BATCH * HID * 2);
    u16* halo = (u16*)alloc((size_t)BATCH * HID * 2);
    u16* hbhi = (u16*)alloc((size_t)BATCH * HID * 2);
    u16* hblo = (u16*)alloc((size_t)BATCH * HID * 2);

    // layer 0: K=342 (11 chunks), M=512 -> grid (16, 32)
    layer_direct<11, 360, 0, 1><<<dim3(BATCH / 16, HID / 16), 256, 0, stream>>>(
        W0, IN_FEAT, HID, HID, x, nullptr, nullptr, b0, hahi, halo, nullptr);

    // layer 1: K=512 (16 chunks), M=512 -> grid (16, 32)
    layer_direct<16, 520, 0, 0><<<dim3(BATCH / 16, HID / 16), 256, 0, stream>>>(
        W1, HID, HID, HID, x, hahi, halo, b1, hbhi, hblo, nullptr);

    // layer 2: K=512, M=311 (20 o-tiles) -> grid (16, 20)
    layer_direct<16, 520, 1, 0><<<dim3(BATCH / 16, 20), 256, 0, stream>>>(
        W2, HID, OUTD, OUTD, x, hbhi, hblo, b2, nullptr, nullptr, out);
}